// Round 1
// baseline (1139.758 us; speedup 1.0000x reference)
//
#include <hip/hip_runtime.h>
#include <hip/hip_bf16.h>

// Conv2d via im2col == GEMM: Y[o, w] = sum_k X[w,k] * W[o,k] + b[o]
// O=512, K=49, Wn=262144. Output packed [O*Wn] fp32.
//
// Strategy (round 1, fp32 VALU baseline):
//  - 1 thread per window. 49 X values live in VGPRs, reused across all 512
//    channels -> enc_x read from HBM exactly once (51 MB).
//  - Weights/bias indexed wave-uniformly -> scalar loads (s_load) on the
//    scalar pipe, consumed directly as the SGPR operand of v_fmac_f32.
//  - Stores coalesced: lane i writes out[o*Wn + blockBase + i].

#define KK 49

__global__ __launch_bounds__(256) void conv_im2col_kernel(
    const float* __restrict__ x,    // [Wn, 49]
    const float* __restrict__ wgt,  // [O, 49]  (O x 7 x 7 flattened)
    const float* __restrict__ bias, // [O]
    float* __restrict__ out,        // [O, Wn] flattened
    int windows, int ochannels)
{
    const int w = blockIdx.x * blockDim.x + threadIdx.x;
    if (w >= windows) return;

    // Pull this window's 49 im2col values into registers (one-time cost,
    // amortized over 512 channels = 25088 FMAs).
    float xv[KK];
    const float* xp = x + (size_t)w * KK;
#pragma unroll
    for (int k = 0; k < KK; ++k) xv[k] = xp[k];

    // Channel loop: 49 FMAs each, weights via scalar path.
    // unroll 2 -> two independent accumulator chains for ILP without
    // exceeding the SGPR budget (2x49 weight scalars in flight).
#pragma unroll 2
    for (int o = 0; o < ochannels; ++o) {
        float acc = bias[o];
        const float* wp = wgt + o * KK;
#pragma unroll
        for (int k = 0; k < KK; ++k) {
            acc = fmaf(xv[k], wp[k], acc);
        }
        out[(size_t)o * windows + w] = acc;
    }
}

extern "C" void kernel_launch(void* const* d_in, const int* in_sizes, int n_in,
                              void* d_out, int out_size, void* d_ws, size_t ws_size,
                              hipStream_t stream) {
    const float* x    = (const float*)d_in[0];  // enc_x [Wn*49]
    const float* wgt  = (const float*)d_in[1];  // weight [O*49]
    const float* bias = (const float*)d_in[2];  // bias [O]
    // d_in[3] = windows_nb (device scalar; sizes derived host-side instead)

    const int windows   = in_sizes[0] / KK;  // 262144
    const int ochannels = in_sizes[1] / KK;  // 512

    float* out = (float*)d_out;

    const int block = 256;
    const int grid  = (windows + block - 1) / block;
    conv_im2col_kernel<<<grid, block, 0, stream>>>(x, wgt, bias, out,
                                                   windows, ochannels);
}

// Round 2
// 668.063 us; speedup vs baseline: 1.7061x; 1.7061x over previous
//
#include <hip/hip_runtime.h>
#include <hip/hip_bf16.h>

// Conv2d via im2col == GEMM: Y[o, w] = sum_k X[w,k] * W[o,k] + b[o]
// O=512, K=49, Wn=262144. Output packed [O*Wn] fp32.
//
// Round 2: latency fix.
//  R1 was latency-bound (VALUBusy 24%, HBM 9.5%, occ 26%): weight s_loads
//  from L2 (~300 cyc) stalled every 2-channel unroll, and 1024 blocks gave
//  only ~2 waves/SIMD to hide it.
//  - Weights for a 64-channel group staged in LDS once per block; inner loop
//    reads them as wave-uniform ds_read_b128 (broadcast, lgkmcnt-pipelined,
//    no SGPR pressure).
//  - Channel dim split into 8 groups -> 8192 blocks = 32 blocks/CU.
//  - 4 channels per k-sweep = 4 independent FMA chains (4-cyc dep latency
//    covered at 2-cyc issue).
//  - X re-read 8x lands in L3 (51 MB << 256 MB).

#define KK 49
#define KP 52   // padded channel stride in LDS floats: 52*4 B = 208 B, 16B-aligned
#define OPC 64  // output channels per block

__global__ __launch_bounds__(256) void conv_im2col_kernel(
    const float* __restrict__ x,    // [Wn, 49]
    const float* __restrict__ wgt,  // [O, 49]
    const float* __restrict__ bias, // [O]
    float* __restrict__ out,        // [O, Wn] flattened
    int windows, int ochannels)
{
    __shared__ __align__(16) float ws[OPC][KP];
    __shared__ float bs[OPC];

    const int tid   = threadIdx.x;
    const int obase = blockIdx.y * OPC;

    // Stage this group's weights + bias into LDS (once per block).
    for (int idx = tid; idx < OPC * KK; idx += 256) {
        int ch = idx / KK;
        int k  = idx - ch * KK;
        ws[ch][k] = wgt[(size_t)(obase + ch) * KK + k];
    }
    if (tid < OPC) bs[tid] = bias[obase + tid];
    __syncthreads();

    const int w = blockIdx.x * 256 + tid;
    if (w >= windows) return;

    // This window's 49 im2col values -> VGPRs (reused for 64 channels here;
    // the row itself is re-read by the other 7 channel groups via L3).
    float xv[KK];
    const float* xp = x + (size_t)w * KK;
#pragma unroll
    for (int k = 0; k < KK; ++k) xv[k] = xp[k];

    float* outp = out + (size_t)obase * windows + w;

    for (int og = 0; og < OPC; og += 4) {
        float acc0 = bs[og + 0];
        float acc1 = bs[og + 1];
        float acc2 = bs[og + 2];
        float acc3 = bs[og + 3];

#pragma unroll
        for (int k = 0; k < 48; k += 4) {
            float4 w0 = *(const float4*)&ws[og + 0][k];
            float4 w1 = *(const float4*)&ws[og + 1][k];
            float4 w2 = *(const float4*)&ws[og + 2][k];
            float4 w3 = *(const float4*)&ws[og + 3][k];
            acc0 = fmaf(xv[k+0], w0.x, acc0);
            acc1 = fmaf(xv[k+0], w1.x, acc1);
            acc2 = fmaf(xv[k+0], w2.x, acc2);
            acc3 = fmaf(xv[k+0], w3.x, acc3);
            acc0 = fmaf(xv[k+1], w0.y, acc0);
            acc1 = fmaf(xv[k+1], w1.y, acc1);
            acc2 = fmaf(xv[k+1], w2.y, acc2);
            ac3:;
            acc3 = fmaf(xv[k+1], w3.y, acc3);
            acc0 = fmaf(xv[k+2], w0.z, acc0);
            acc1 = fmaf(xv[k+2], w1.z, acc1);
            acc2 = fmaf(xv[k+2], w2.z, acc2);
            acc3 = fmaf(xv[k+2], w3.z, acc3);
            acc0 = fmaf(xv[k+3], w0.w, acc0);
            acc1 = fmaf(xv[k+3], w1.w, acc1);
            acc2 = fmaf(xv[k+3], w2.w, acc2);
            acc3 = fmaf(xv[k+3], w3.w, acc3);
        }
        // k = 48 tail
        acc0 = fmaf(xv[48], ws[og + 0][48], acc0);
        acc1 = fmaf(xv[48], ws[og + 1][48], acc1);
        acc2 = fmaf(xv[48], ws[og + 2][48], acc2);
        acc3 = fmaf(xv[48], ws[og + 3][48], acc3);

        outp[(size_t)(og + 0) * windows] = acc0;
        outp[(size_t)(og + 1) * windows] = acc1;
        outp[(size_t)(og + 2) * windows] = acc2;
        outp[(size_t)(og + 3) * windows] = acc3;
    }
}

extern "C" void kernel_launch(void* const* d_in, const int* in_sizes, int n_in,
                              void* d_out, int out_size, void* d_ws, size_t ws_size,
                              hipStream_t stream) {
    const float* x    = (const float*)d_in[0];  // enc_x [Wn*49]
    const float* wgt  = (const float*)d_in[1];  // weight [O*49]
    const float* bias = (const float*)d_in[2];  // bias [O]

    const int windows   = in_sizes[0] / KK;  // 262144
    const int ochannels = in_sizes[1] / KK;  // 512

    float* out = (float*)d_out;

    dim3 block(256);
    dim3 grid((windows + 255) / 256, ochannels / OPC);
    conv_im2col_kernel<<<grid, block, 0, stream>>>(x, wgt, bias, out,
                                                   windows, ochannels);
}